// Round 1
// 611.785 us; speedup vs baseline: 1.1459x; 1.1459x over previous
//
#include <hip/hip_runtime.h>
#include <stdint.h>

#define NB 64
#define MM 128
#define LL 8192
#define DD 64

using f32x4 = __attribute__((ext_vector_type(4))) float;
using bf16x8 = __attribute__((ext_vector_type(8))) short;

__device__ __forceinline__ float bf2f(uint32_t u16) {
    uint32_t v = u16 << 16;
    float f;
    __builtin_memcpy(&f, &v, 4);
    return f;
}
__device__ __forceinline__ uint16_t f2bf(float f) {
    uint32_t x;
    __builtin_memcpy(&x, &f, 4);
    uint32_t r = x + 0x7FFFu + ((x >> 16) & 1u);
    return (uint16_t)(r >> 16);
}
// runtime-dtype scalar/vec4 loads (bf = "input array is bf16")
__device__ __forceinline__ float ldf(const void* p, size_t i, bool bf) {
    if (bf) return bf2f(((const uint16_t*)p)[i]);
    return ((const float*)p)[i];
}
__device__ __forceinline__ float4 ldf4(const void* p, size_t i, bool bf) {  // i must be 4-aligned
    if (bf) {
        uint2 u = *(const uint2*)((const uint16_t*)p + i);
        return make_float4(bf2f(u.x & 0xffffu), bf2f(u.x >> 16), bf2f(u.y & 0xffffu),
                           bf2f(u.y >> 16));
    }
    return *(const float4*)((const float*)p + i);
}
// fixed bf16 x4 load (internal ws tensors)
__device__ __forceinline__ float4 ldb4(const uint16_t* p, size_t i) {
    uint2 u = *(const uint2*)(p + i);
    return make_float4(bf2f(u.x & 0xffffu), bf2f(u.x >> 16), bf2f(u.y & 0xffffu), bf2f(u.y >> 16));
}

// ---- K0: detect whether float inputs are bf16 (flag=1) or fp32 (flag=0) ----
__global__ __launch_bounds__(256) void k_detect(const uint32_t* __restrict__ p,
                                                int* __restrict__ flag) {
    int t = threadIdx.x;
    int cnt = 0, nz = 0;
    for (int i = t; i < 16384; i += 256) {
        uint32_t w = p[64 + i];
        uint32_t lo = w & 0xffffu;
        if (lo) {
            nz++;
            uint32_t e = (lo >> 7) & 0xffu;
            if (e >= 100 && e <= 130) cnt++;
        }
    }
#pragma unroll
    for (int off = 32; off; off >>= 1) {
        cnt += __shfl_xor(cnt, off, 64);
        nz += __shfl_xor(nz, off, 64);
    }
    __shared__ int sc[4], sn[4];
    if ((t & 63) == 0) {
        sc[t >> 6] = cnt;
        sn[t >> 6] = nz;
    }
    __syncthreads();
    if (t == 0) {
        int C = sc[0] + sc[1] + sc[2] + sc[3];
        int Z = sn[0] + sn[1] + sn[2] + sn[3];
        flag[0] = (2 * C > Z) ? 1 : 0;
    }
}

// ---- K0b: W_out -> bf16 hi + bf16 residual (split-precision for MFMA) ----
// 8192*64 = 524288 elems, processed 4 at a time: grid 512 x 256.
__global__ __launch_bounds__(256) void k_wprep(const void* __restrict__ Wout,
                                               const int* __restrict__ flag,
                                               uint16_t* __restrict__ whi,
                                               uint16_t* __restrict__ wlo) {
    bool bf = flag[0] != 0;
    int i = blockIdx.x * 256 + threadIdx.x;  // group of 4 elems
    if (bf) {
        uint2 u = *((const uint2*)Wout + i);
        *((uint2*)whi + i) = u;
        *((uint2*)wlo + i) = make_uint2(0u, 0u);
    } else {
        float4 f = *((const float4*)Wout + i);
        uint16_t h0 = f2bf(f.x), h1 = f2bf(f.y), h2 = f2bf(f.z), h3 = f2bf(f.w);
        *((uint2*)whi + i) = make_uint2((uint32_t)h0 | ((uint32_t)h1 << 16),
                                        (uint32_t)h2 | ((uint32_t)h3 << 16));
        uint16_t l0 = f2bf(f.x - bf2f(h0)), l1 = f2bf(f.y - bf2f(h1));
        uint16_t l2 = f2bf(f.z - bf2f(h2)), l3 = f2bf(f.w - bf2f(h3));
        *((uint2*)wlo + i) = make_uint2((uint32_t)l0 | ((uint32_t)l1 << 16),
                                        (uint32_t)l2 | ((uint32_t)l3 << 16));
    }
}

// ---------------- K1: row sums of mat2s (L x L) -> rowsum[L] fp32 ----------------
__global__ __launch_bounds__(256) void k_rowsum(const void* __restrict__ mat2s,
                                                const int* __restrict__ flag,
                                                float* __restrict__ rowsum) {
    bool bf = flag[0] != 0;
    int row = blockIdx.x;
    float s = 0.f;
    if (bf) {
        const uint4* p4 = (const uint4*)((const uint16_t*)mat2s + (size_t)row * LL);
#pragma unroll
        for (int c = 0; c < 4; c++) {
            uint4 u = p4[c * 256 + threadIdx.x];
            uint32_t w[4] = {u.x, u.y, u.z, u.w};
#pragma unroll
            for (int q = 0; q < 4; q++) s += bf2f(w[q] & 0xffffu) + bf2f(w[q] >> 16);
        }
    } else {
        const float4* p4 = (const float4*)((const float*)mat2s + (size_t)row * LL);
#pragma unroll
        for (int c = 0; c < 8; c++) {
            float4 v = p4[c * 256 + threadIdx.x];
            s += v.x + v.y + v.z + v.w;
        }
    }
#pragma unroll
    for (int off = 32; off; off >>= 1) s += __shfl_xor(s, off, 64);
    __shared__ float red[4];
    if ((threadIdx.x & 63) == 0) red[threadIdx.x >> 6] = s;
    __syncthreads();
    if (threadIdx.x == 0) rowsum[row] = red[0] + red[1] + red[2] + red[3];
}

// ---------------- K2a: joint = emb gather; q,k,v = joint @ W.T (per batch) ----------------
__global__ __launch_bounds__(256) void k_qkv(
    const int* __restrict__ traj, const int* __restrict__ flag, const void* __restrict__ emb_t,
    const void* __restrict__ emb_l, const void* __restrict__ emb_u, const void* __restrict__ Wq,
    const void* __restrict__ Wk, const void* __restrict__ Wv, uint16_t* __restrict__ qg,
    uint16_t* __restrict__ kg, uint16_t* __restrict__ vg) {
    bool bf = flag[0] != 0;
    int n = blockIdx.x;
    int t = threadIdx.x;
    __shared__ float joint[MM][DD + 4];
    __shared__ float Wl[DD][DD + 4];
    __shared__ int iu[MM], il[MM], it[MM];

    if (t < MM) {
        iu[t] = traj[((size_t)(n * MM + t)) * 3 + 0];
        il[t] = traj[((size_t)(n * MM + t)) * 3 + 1];
        int tm = traj[((size_t)(n * MM + t)) * 3 + 2];
        it[t] = (tm - 1) % 168 + 1;
    }
    __syncthreads();

    for (int i = t; i < MM * 16; i += 256) {
        int m = i >> 4, c = (i & 15) * 4;
        float4 a = ldf4(emb_t, (size_t)it[m] * DD + c, bf);
        float4 b = ldf4(emb_l, (size_t)il[m] * DD + c, bf);
        float4 d = ldf4(emb_u, (size_t)iu[m] * DD + c, bf);
        joint[m][c]     = a.x + b.x + d.x;
        joint[m][c + 1] = a.y + b.y + d.y;
        joint[m][c + 2] = a.z + b.z + d.z;
        joint[m][c + 3] = a.w + b.w + d.w;
    }

    const void* Ws[3] = {Wq, Wk, Wv};
    uint16_t* outs[3] = {qg, kg, vg};
    int m = t >> 1;
    int dbase = (t & 1) * 32;

    for (int w = 0; w < 3; w++) {
        __syncthreads();
        for (int i = t; i < DD * 16; i += 256) {
            int r = i >> 4, c = (i & 15) * 4;
            float4 a = ldf4(Ws[w], (size_t)r * DD + c, bf);
            Wl[r][c] = a.x;
            Wl[r][c + 1] = a.y;
            Wl[r][c + 2] = a.z;
            Wl[r][c + 3] = a.w;
        }
        __syncthreads();
        float acc[32];
#pragma unroll
        for (int j = 0; j < 32; j++) acc[j] = 0.f;
        for (int kk = 0; kk < DD; kk += 4) {
            float4 j4 = *(const float4*)&joint[m][kk];
#pragma unroll
            for (int j = 0; j < 32; j++) {
                float4 w4 = *(const float4*)&Wl[dbase + j][kk];
                acc[j] += j4.x * w4.x + j4.y * w4.y + j4.z * w4.z + j4.w * w4.w;
            }
        }
        uint32_t* og = (uint32_t*)(outs[w] + ((size_t)(n * MM + m)) * DD + dbase);
#pragma unroll
        for (int j = 0; j < 32; j += 2)
            og[j >> 1] = (uint32_t)f2bf(acc[j]) | ((uint32_t)f2bf(acc[j + 1]) << 16);
    }
}

// ---------------- K2b: attention + delta scalars + h = self_attn * delta2 ----------------
__global__ __launch_bounds__(256) void k_attn(
    const int* __restrict__ traj, const int* __restrict__ traj_len, const int* __restrict__ flag,
    const void* __restrict__ mat1, const void* __restrict__ vec, const void* __restrict__ emb_su,
    const void* __restrict__ emb_sl, const void* __restrict__ emb_tu,
    const void* __restrict__ emb_tl, const float* __restrict__ rowsum,
    const uint16_t* __restrict__ qg, const uint16_t* __restrict__ kg,
    const uint16_t* __restrict__ vg, uint16_t* __restrict__ hg) {
    bool bf = flag[0] != 0;
    int chunk = blockIdx.x;  // 0..3 (32 rows each)
    int n = blockIdx.y;
    int t = threadIdx.x;
    __shared__ float kl[MM][DD + 4];
    __shared__ float vl[MM][DD + 4];
    __shared__ float ql[32][DD + 4];
    __shared__ float attn[32][MM + 4];

    int len = traj_len[n];

    for (int i = t; i < MM * 16; i += 256) {
        int r = i >> 4, c = (i & 15) * 4;
        *(float4*)&kl[r][c] = ldb4(kg, ((size_t)(n * MM + r)) * DD + c);
        *(float4*)&vl[r][c] = ldb4(vg, ((size_t)(n * MM + r)) * DD + c);
    }
    for (int i = t; i < 32 * 16; i += 256) {
        int r = i >> 4, c = (i & 15) * 4;
        *(float4*)&ql[r][c] = ldb4(qg, ((size_t)(n * MM + chunk * 32 + r)) * DD + c);
    }
    float ssl = 0.f, ssu = 0.f, stl = 0.f, stu = 0.f;
    for (int d = 0; d < DD; d++) {
        ssl += ldf(emb_sl, DD + d, bf);
        ssu += ldf(emb_su, DD + d, bf);
        stl += ldf(emb_tl, DD + d, bf);
        stu += ldf(emb_tu, DD + d, bf);
    }
    __syncthreads();

    int tx = t & 15, ty = t >> 4;
    float sc[2][8];
#pragma unroll
    for (int i = 0; i < 2; i++)
#pragma unroll
        for (int j = 0; j < 8; j++) sc[i][j] = 0.f;

    for (int kk = 0; kk < DD; kk += 4) {
        float4 q4[2], k4[8];
#pragma unroll
        for (int i = 0; i < 2; i++) q4[i] = *(const float4*)&ql[ty + 16 * i][kk];
#pragma unroll
        for (int j = 0; j < 8; j++) k4[j] = *(const float4*)&kl[tx + 16 * j][kk];
#pragma unroll
        for (int i = 0; i < 2; i++)
#pragma unroll
            for (int j = 0; j < 8; j++)
                sc[i][j] += q4[i].x * k4[j].x + q4[i].y * k4[j].y + q4[i].z * k4[j].z +
                            q4[i].w * k4[j].w;
    }
#pragma unroll
    for (int i = 0; i < 2; i++) {
        int m = chunk * 32 + ty + 16 * i;
        bool vm = m < len;
#pragma unroll
        for (int j = 0; j < 8; j++) {
            int p = tx + 16 * j;
            size_t base = (((size_t)(n * MM + m)) * MM + p) * 2;
            float ds = ldf(mat1, base, bf);
            float dt = ldf(mat1, base + 1, bf);
            bool v2 = vm && (p < len);
            float del = v2 ? ((ssl * (100.f - ds) + ssu * ds) * 0.01f +
                              (stl * (500.f - dt) + stu * dt) * 0.002f)
                           : 0.f;
            sc[i][j] += del;
        }
    }
    // softmax over all 128 cols, then post-softmax ragged mask
#pragma unroll
    for (int i = 0; i < 2; i++) {
        float mx = sc[i][0];
#pragma unroll
        for (int j = 1; j < 8; j++) mx = fmaxf(mx, sc[i][j]);
#pragma unroll
        for (int off = 1; off < 16; off <<= 1) mx = fmaxf(mx, __shfl_xor(mx, off, 64));
        float sum = 0.f;
#pragma unroll
        for (int j = 0; j < 8; j++) {
            sc[i][j] = __expf(sc[i][j] - mx);
            sum += sc[i][j];
        }
#pragma unroll
        for (int off = 1; off < 16; off <<= 1) sum += __shfl_xor(sum, off, 64);
        float inv = 1.f / sum;
        int m = chunk * 32 + ty + 16 * i;
        bool vm = m < len;
#pragma unroll
        for (int j = 0; j < 8; j++) {
            int p = tx + 16 * j;
            attn[ty + 16 * i][p] = (vm && p < len) ? sc[i][j] * inv : 0.f;
        }
    }
    __syncthreads();

    float pv[2][4];
#pragma unroll
    for (int i = 0; i < 2; i++)
#pragma unroll
        for (int u = 0; u < 4; u++) pv[i][u] = 0.f;

    for (int pp = 0; pp < MM; pp += 4) {
        float4 a4[2], v4[4];
#pragma unroll
        for (int i = 0; i < 2; i++) a4[i] = *(const float4*)&attn[ty + 16 * i][pp];
#pragma unroll
        for (int u = 0; u < 4; u++) v4[u] = *(const float4*)&vl[pp + u][4 * tx];
#pragma unroll
        for (int i = 0; i < 2; i++) {
            pv[i][0] += a4[i].x * v4[0].x + a4[i].y * v4[1].x + a4[i].z * v4[2].x + a4[i].w * v4[3].x;
            pv[i][1] += a4[i].x * v4[0].y + a4[i].y * v4[1].y + a4[i].z * v4[2].y + a4[i].w * v4[3].y;
            pv[i][2] += a4[i].x * v4[0].z + a4[i].y * v4[1].z + a4[i].z * v4[2].z + a4[i].w * v4[3].z;
            pv[i][3] += a4[i].x * v4[0].w + a4[i].y * v4[1].w + a4[i].z * v4[2].w + a4[i].w * v4[3].w;
        }
    }

#pragma unroll
    for (int i = 0; i < 2; i++) {
        int m = chunk * 32 + ty + 16 * i;
        bool vm = m < len;
        int m1 = vm ? 1 : 0;
        int loc = traj[((size_t)(n * MM + m)) * 3 + 1];
        float rs = vm ? rowsum[loc - 1] : 0.f;
        float vv = ldf(vec, (size_t)(n * MM + m), bf);
        float Svsl = rs;
        float Svsu = 100.f * 8192.f - rs;
        float Svtl = vv * 8192.f;
        float Svtu = (500.f - vv) * 8192.f;
        uint32_t pk[2];
        float hv[4];
#pragma unroll
        for (int u = 0; u < 4; u++) {
            int d = 4 * tx + u;
            float esl = ldf(emb_sl, m1 * DD + d, bf);
            float esu = ldf(emb_su, m1 * DD + d, bf);
            float etl = ldf(emb_tl, m1 * DD + d, bf);
            float etu = ldf(emb_tu, m1 * DD + d, bf);
            float d2 = (esl * Svsu + esu * Svsl) * 0.01f + (etl * Svtu + etu * Svtl) * 0.002f;
            hv[u] = pv[i][u] * d2;
        }
        pk[0] = (uint32_t)f2bf(hv[0]) | ((uint32_t)f2bf(hv[1]) << 16);
        pk[1] = (uint32_t)f2bf(hv[2]) | ((uint32_t)f2bf(hv[3]) << 16);
        *(uint2*)(hg + ((size_t)(n * MM + m)) * DD + 4 * tx) = make_uint2(pk[0], pk[1]);
    }
}

// ---------------- K3: out = h @ W_out.T + b_out  (8192x64 @ 64x8192), bf16 MFMA ----------------
// h is already bf16 (hg); W_out pre-split into whi+wlo bf16 planes (k_wprep), so the
// only rounding vs the previous fp32-VALU version is ~2^-16-relative on W_out.
// A/B fragments (16x16x32): lane&15 -> row (A) / col (B), (lane>>4)*8 -> k-base, 8
// contiguous bf16 per lane == one 16B global load from the row-major K=64 tensors.
// C/D: col=lane&15, row=(lane>>4)*4+reg (m89-verified) -> transposed through wave-private
// LDS (stride 68: 2-way conflicts only, free) into coalesced float4 row stores.
__global__ __launch_bounds__(256, 2) void k_out(const uint16_t* __restrict__ hg,
                                                const int* __restrict__ flag,
                                                const uint16_t* __restrict__ whi,
                                                const uint16_t* __restrict__ wlo,
                                                const void* __restrict__ bout,
                                                void* __restrict__ out) {
    bool bf = flag[0] != 0;
    int ct = blockIdx.x;
    int rt = blockIdx.y;
    int t = threadIdx.x;
    int w = t >> 6, l = t & 63;
    int wr = w >> 1, wc = w & 1;
    int row0 = rt * 128 + wr * 64;  // wave's 64x64 output tile origin
    int col0 = ct * 128 + wc * 64;
    int lr = l & 15;          // row (A) / col (B) within 16-tile
    int kb = (l >> 4) * 8;    // k-base within 32-slice

    f32x4 acc[4][4];
#pragma unroll
    for (int i = 0; i < 4; i++)
#pragma unroll
        for (int j = 0; j < 4; j++) acc[i][j] = (f32x4){0.f, 0.f, 0.f, 0.f};

#pragma unroll
    for (int s = 0; s < 2; s++) {  // two K=32 slices of K=64
        bf16x8 af[4], bh[4], bl[4];
#pragma unroll
        for (int i = 0; i < 4; i++)
            af[i] = *(const bf16x8*)(hg + (size_t)(row0 + i * 16 + lr) * DD + s * 32 + kb);
#pragma unroll
        for (int j = 0; j < 4; j++) {
            bh[j] = *(const bf16x8*)(whi + (size_t)(col0 + j * 16 + lr) * DD + s * 32 + kb);
            bl[j] = *(const bf16x8*)(wlo + (size_t)(col0 + j * 16 + lr) * DD + s * 32 + kb);
        }
#pragma unroll
        for (int i = 0; i < 4; i++)
#pragma unroll
            for (int j = 0; j < 4; j++) {
                acc[i][j] = __builtin_amdgcn_mfma_f32_16x16x32_bf16(af[i], bh[j], acc[i][j], 0, 0, 0);
                acc[i][j] = __builtin_amdgcn_mfma_f32_16x16x32_bf16(af[i], bl[j], acc[i][j], 0, 0, 0);
            }
    }

    // wave-private LDS transpose (no barrier needed: each wave reads only its own quadrant)
    __shared__ float st[4][64][68];
#pragma unroll
    for (int i = 0; i < 4; i++)
#pragma unroll
        for (int j = 0; j < 4; j++)
#pragma unroll
            for (int q = 0; q < 4; q++)
                st[w][i * 16 + (l >> 4) * 4 + q][j * 16 + lr] = acc[i][j][q];

    // bias for this lane's 4 contiguous output cols in the readback layout
    int cb = col0 + (l & 15) * 4;
    float b0 = ldf(bout, cb + 0, bf), b1 = ldf(bout, cb + 1, bf);
    float b2 = ldf(bout, cb + 2, bf), b3 = ldf(bout, cb + 3, bf);

#pragma unroll
    for (int it = 0; it < 16; it++) {
        int r = it * 4 + (l >> 4);
        float4 v = *(const float4*)&st[w][r][(l & 15) * 4];
        v.x += b0;
        v.y += b1;
        v.z += b2;
        v.w += b3;
        size_t gr = (size_t)(row0 + r) * LL + cb;
        if (bf) {
            uint32_t p0 = (uint32_t)f2bf(v.x) | ((uint32_t)f2bf(v.y) << 16);
            uint32_t p1 = (uint32_t)f2bf(v.z) | ((uint32_t)f2bf(v.w) << 16);
            *(uint2*)((uint16_t*)out + gr) = make_uint2(p0, p1);
        } else {
            *(float4*)((float*)out + gr) = v;
        }
    }
}

extern "C" void kernel_launch(void* const* d_in, const int* in_sizes, int n_in,
                              void* d_out, int out_size, void* d_ws, size_t ws_size,
                              hipStream_t stream) {
    const int* traj     = (const int*)d_in[0];
    const void* mat1    = d_in[1];
    const void* mat2s   = d_in[2];
    const void* vec     = d_in[3];
    const int* traj_len = (const int*)d_in[4];
    const void* emb_t   = d_in[5];
    const void* emb_l   = d_in[6];
    const void* emb_u   = d_in[7];
    const void* emb_su  = d_in[8];
    const void* emb_sl  = d_in[9];
    const void* emb_tu  = d_in[10];
    const void* emb_tl  = d_in[11];
    const void* Wq      = d_in[12];
    const void* Wk      = d_in[13];
    const void* Wv      = d_in[14];
    const void* Wout    = d_in[15];
    const void* bout    = d_in[16];

    // ws layout: flag (64B) | rowsum 8192 f32 (32KB) | q,k,v,h bf16 (1MB each)
    //            | wout_hi bf16 (1MB) | wout_lo bf16 (1MB)  ≈ 6.25MB
    char* W = (char*)d_ws;
    int* flag = (int*)W;
    float* rowsum = (float*)(W + 64);
    uint16_t* qg = (uint16_t*)(W + 64 + 32768);
    uint16_t* kg = qg + (size_t)LL * DD;
    uint16_t* vg = kg + (size_t)LL * DD;
    uint16_t* hg = vg + (size_t)LL * DD;
    uint16_t* whi = hg + (size_t)LL * DD;
    uint16_t* wlo = whi + (size_t)LL * DD;

    k_detect<<<dim3(1), dim3(256), 0, stream>>>((const uint32_t*)emb_l, flag);
    k_wprep<<<dim3(512), dim3(256), 0, stream>>>(Wout, flag, whi, wlo);
    k_rowsum<<<dim3(LL), dim3(256), 0, stream>>>(mat2s, flag, rowsum);
    k_qkv<<<dim3(NB), dim3(256), 0, stream>>>(traj, flag, emb_t, emb_l, emb_u, Wq, Wk, Wv, qg, kg,
                                              vg);
    k_attn<<<dim3(4, NB), dim3(256), 0, stream>>>(traj, traj_len, flag, mat1, vec, emb_su, emb_sl,
                                                  emb_tu, emb_tl, rowsum, qg, kg, vg, hg);
    k_out<<<dim3(64, 64), dim3(256), 0, stream>>>(hg, flag, whi, wlo, bout, d_out);
}

// Round 2
// 570.609 us; speedup vs baseline: 1.2285x; 1.0722x over previous
//
#include <hip/hip_runtime.h>
#include <stdint.h>

#define NB 64
#define MM 128
#define LL 8192
#define DD 64

using f32x4 = __attribute__((ext_vector_type(4))) float;
using bf16x8 = __attribute__((ext_vector_type(8))) short;

__device__ __forceinline__ float bf2f(uint32_t u16) {
    uint32_t v = u16 << 16;
    float f;
    __builtin_memcpy(&f, &v, 4);
    return f;
}
__device__ __forceinline__ uint16_t f2bf(float f) {
    uint32_t x;
    __builtin_memcpy(&x, &f, 4);
    uint32_t r = x + 0x7FFFu + ((x >> 16) & 1u);
    return (uint16_t)(r >> 16);
}
// runtime-dtype scalar/vec4 loads (bf = "input array is bf16")
__device__ __forceinline__ float ldf(const void* p, size_t i, bool bf) {
    if (bf) return bf2f(((const uint16_t*)p)[i]);
    return ((const float*)p)[i];
}
__device__ __forceinline__ float4 ldf4(const void* p, size_t i, bool bf) {  // i must be 4-aligned
    if (bf) {
        uint2 u = *(const uint2*)((const uint16_t*)p + i);
        return make_float4(bf2f(u.x & 0xffffu), bf2f(u.x >> 16), bf2f(u.y & 0xffffu),
                           bf2f(u.y >> 16));
    }
    return *(const float4*)((const float*)p + i);
}
// fixed bf16 x4 load (internal ws tensors)
__device__ __forceinline__ float4 ldb4(const uint16_t* p, size_t i) {
    uint2 u = *(const uint2*)(p + i);
    return make_float4(bf2f(u.x & 0xffffu), bf2f(u.x >> 16), bf2f(u.y & 0xffffu), bf2f(u.y >> 16));
}

// ---- K0: detect whether float inputs are bf16 (flag=1) or fp32 (flag=0) ----
// 4096 words sampled: exponent-in-[100,130] rate for the low halfword is ~100% for bf16
// (values ~N(0, .02)) vs ~12% for fp32 random mantissa bits -> huge margin.
__global__ __launch_bounds__(256) void k_detect(const uint32_t* __restrict__ p,
                                                int* __restrict__ flag) {
    int t = threadIdx.x;
    int cnt = 0, nz = 0;
    for (int i = t; i < 4096; i += 256) {
        uint32_t w = p[64 + i];
        uint32_t lo = w & 0xffffu;
        if (lo) {
            nz++;
            uint32_t e = (lo >> 7) & 0xffu;
            if (e >= 100 && e <= 130) cnt++;
        }
    }
#pragma unroll
    for (int off = 32; off; off >>= 1) {
        cnt += __shfl_xor(cnt, off, 64);
        nz += __shfl_xor(nz, off, 64);
    }
    __shared__ int sc[4], sn[4];
    if ((t & 63) == 0) {
        sc[t >> 6] = cnt;
        sn[t >> 6] = nz;
    }
    __syncthreads();
    if (t == 0) {
        int C = sc[0] + sc[1] + sc[2] + sc[3];
        int Z = sn[0] + sn[1] + sn[2] + sn[3];
        flag[0] = (2 * C > Z) ? 1 : 0;
    }
}

// ---- K0b: W_out -> bf16 hi + bf16 residual (split-precision for MFMA) ----
__global__ __launch_bounds__(256) void k_wprep(const void* __restrict__ Wout,
                                               const int* __restrict__ flag,
                                               uint16_t* __restrict__ whi,
                                               uint16_t* __restrict__ wlo) {
    bool bf = flag[0] != 0;
    int i = blockIdx.x * 256 + threadIdx.x;  // group of 4 elems
    if (bf) {
        uint2 u = *((const uint2*)Wout + i);
        *((uint2*)whi + i) = u;
        *((uint2*)wlo + i) = make_uint2(0u, 0u);
    } else {
        float4 f = *((const float4*)Wout + i);
        uint16_t h0 = f2bf(f.x), h1 = f2bf(f.y), h2 = f2bf(f.z), h3 = f2bf(f.w);
        *((uint2*)whi + i) = make_uint2((uint32_t)h0 | ((uint32_t)h1 << 16),
                                        (uint32_t)h2 | ((uint32_t)h3 << 16));
        uint16_t l0 = f2bf(f.x - bf2f(h0)), l1 = f2bf(f.y - bf2f(h1));
        uint16_t l2 = f2bf(f.z - bf2f(h2)), l3 = f2bf(f.w - bf2f(h3));
        *((uint2*)wlo + i) = make_uint2((uint32_t)l0 | ((uint32_t)l1 << 16),
                                        (uint32_t)l2 | ((uint32_t)l3 << 16));
    }
}

// ---------------- K1: row sums of mat2s (L x L) -> rowsum[L] fp32 ----------------
__global__ __launch_bounds__(256) void k_rowsum(const void* __restrict__ mat2s,
                                                const int* __restrict__ flag,
                                                float* __restrict__ rowsum) {
    bool bf = flag[0] != 0;
    int row = blockIdx.x;
    float s = 0.f;
    if (bf) {
        const uint4* p4 = (const uint4*)((const uint16_t*)mat2s + (size_t)row * LL);
#pragma unroll
        for (int c = 0; c < 4; c++) {
            uint4 u = p4[c * 256 + threadIdx.x];
            uint32_t w[4] = {u.x, u.y, u.z, u.w};
#pragma unroll
            for (int q = 0; q < 4; q++) s += bf2f(w[q] & 0xffffu) + bf2f(w[q] >> 16);
        }
    } else {
        const float4* p4 = (const float4*)((const float*)mat2s + (size_t)row * LL);
#pragma unroll
        for (int c = 0; c < 8; c++) {
            float4 v = p4[c * 256 + threadIdx.x];
            s += v.x + v.y + v.z + v.w;
        }
    }
#pragma unroll
    for (int off = 32; off; off >>= 1) s += __shfl_xor(s, off, 64);
    __shared__ float red[4];
    if ((threadIdx.x & 63) == 0) red[threadIdx.x >> 6] = s;
    __syncthreads();
    if (threadIdx.x == 0) rowsum[row] = red[0] + red[1] + red[2] + red[3];
}

// ---------------- K2a: joint = emb gather; q,k,v = joint @ W.T ----------------
// grid (NB, 3): one W per block (serial 3-GEMM loop left 75% of CUs idle at grid=64).
__global__ __launch_bounds__(256) void k_qkv(
    const int* __restrict__ traj, const int* __restrict__ flag, const void* __restrict__ emb_t,
    const void* __restrict__ emb_l, const void* __restrict__ emb_u, const void* __restrict__ Wq,
    const void* __restrict__ Wk, const void* __restrict__ Wv, uint16_t* __restrict__ qg,
    uint16_t* __restrict__ kg, uint16_t* __restrict__ vg) {
    bool bf = flag[0] != 0;
    int n = blockIdx.x;
    int w = blockIdx.y;  // 0=q, 1=k, 2=v
    int t = threadIdx.x;
    __shared__ float joint[MM][DD + 4];
    __shared__ float Wl[DD][DD + 4];
    __shared__ int iu[MM], il[MM], it[MM];

    if (t < MM) {
        iu[t] = traj[((size_t)(n * MM + t)) * 3 + 0];
        il[t] = traj[((size_t)(n * MM + t)) * 3 + 1];
        int tm = traj[((size_t)(n * MM + t)) * 3 + 2];
        it[t] = (tm - 1) % 168 + 1;
    }
    const void* Ws[3] = {Wq, Wk, Wv};
    uint16_t* outs[3] = {qg, kg, vg};
    for (int i = t; i < DD * 16; i += 256) {
        int r = i >> 4, c = (i & 15) * 4;
        float4 a = ldf4(Ws[w], (size_t)r * DD + c, bf);
        Wl[r][c] = a.x;
        Wl[r][c + 1] = a.y;
        Wl[r][c + 2] = a.z;
        Wl[r][c + 3] = a.w;
    }
    __syncthreads();

    for (int i = t; i < MM * 16; i += 256) {
        int m = i >> 4, c = (i & 15) * 4;
        float4 a = ldf4(emb_t, (size_t)it[m] * DD + c, bf);
        float4 b = ldf4(emb_l, (size_t)il[m] * DD + c, bf);
        float4 d = ldf4(emb_u, (size_t)iu[m] * DD + c, bf);
        joint[m][c]     = a.x + b.x + d.x;
        joint[m][c + 1] = a.y + b.y + d.y;
        joint[m][c + 2] = a.z + b.z + d.z;
        joint[m][c + 3] = a.w + b.w + d.w;
    }
    __syncthreads();

    int m = t >> 1;
    int dbase = (t & 1) * 32;
    float acc[32];
#pragma unroll
    for (int j = 0; j < 32; j++) acc[j] = 0.f;
    for (int kk = 0; kk < DD; kk += 4) {
        float4 j4 = *(const float4*)&joint[m][kk];
#pragma unroll
        for (int j = 0; j < 32; j++) {
            float4 w4 = *(const float4*)&Wl[dbase + j][kk];
            acc[j] += j4.x * w4.x + j4.y * w4.y + j4.z * w4.z + j4.w * w4.w;
        }
    }
    uint32_t* og = (uint32_t*)(outs[w] + ((size_t)(n * MM + m)) * DD + dbase);
#pragma unroll
    for (int j = 0; j < 32; j += 2)
        og[j >> 1] = (uint32_t)f2bf(acc[j]) | ((uint32_t)f2bf(acc[j + 1]) << 16);
}

// ---------------- K2b: attention + delta scalars + h = self_attn * delta2 ----------------
__global__ __launch_bounds__(256) void k_attn(
    const int* __restrict__ traj, const int* __restrict__ traj_len, const int* __restrict__ flag,
    const void* __restrict__ mat1, const void* __restrict__ vec, const void* __restrict__ emb_su,
    const void* __restrict__ emb_sl, const void* __restrict__ emb_tu,
    const void* __restrict__ emb_tl, const float* __restrict__ rowsum,
    const uint16_t* __restrict__ qg, const uint16_t* __restrict__ kg,
    const uint16_t* __restrict__ vg, uint16_t* __restrict__ hg) {
    bool bf = flag[0] != 0;
    int chunk = blockIdx.x;  // 0..3 (32 rows each)
    int n = blockIdx.y;
    int t = threadIdx.x;
    __shared__ float kl[MM][DD + 4];
    __shared__ float vl[MM][DD + 4];
    __shared__ float ql[32][DD + 4];
    __shared__ float attn[32][MM + 4];

    int len = traj_len[n];

    for (int i = t; i < MM * 16; i += 256) {
        int r = i >> 4, c = (i & 15) * 4;
        *(float4*)&kl[r][c] = ldb4(kg, ((size_t)(n * MM + r)) * DD + c);
        *(float4*)&vl[r][c] = ldb4(vg, ((size_t)(n * MM + r)) * DD + c);
    }
    for (int i = t; i < 32 * 16; i += 256) {
        int r = i >> 4, c = (i & 15) * 4;
        *(float4*)&ql[r][c] = ldb4(qg, ((size_t)(n * MM + chunk * 32 + r)) * DD + c);
    }
    float ssl = 0.f, ssu = 0.f, stl = 0.f, stu = 0.f;
    for (int d = 0; d < DD; d++) {
        ssl += ldf(emb_sl, DD + d, bf);
        ssu += ldf(emb_su, DD + d, bf);
        stl += ldf(emb_tl, DD + d, bf);
        stu += ldf(emb_tu, DD + d, bf);
    }
    __syncthreads();

    int tx = t & 15, ty = t >> 4;
    float sc[2][8];
#pragma unroll
    for (int i = 0; i < 2; i++)
#pragma unroll
        for (int j = 0; j < 8; j++) sc[i][j] = 0.f;

    for (int kk = 0; kk < DD; kk += 4) {
        float4 q4[2], k4[8];
#pragma unroll
        for (int i = 0; i < 2; i++) q4[i] = *(const float4*)&ql[ty + 16 * i][kk];
#pragma unroll
        for (int j = 0; j < 8; j++) k4[j] = *(const float4*)&kl[tx + 16 * j][kk];
#pragma unroll
        for (int i = 0; i < 2; i++)
#pragma unroll
            for (int j = 0; j < 8; j++)
                sc[i][j] += q4[i].x * k4[j].x + q4[i].y * k4[j].y + q4[i].z * k4[j].z +
                            q4[i].w * k4[j].w;
    }
#pragma unroll
    for (int i = 0; i < 2; i++) {
        int m = chunk * 32 + ty + 16 * i;
        bool vm = m < len;
#pragma unroll
        for (int j = 0; j < 8; j++) {
            int p = tx + 16 * j;
            size_t base = (((size_t)(n * MM + m)) * MM + p) * 2;
            float ds = ldf(mat1, base, bf);
            float dt = ldf(mat1, base + 1, bf);
            bool v2 = vm && (p < len);
            float del = v2 ? ((ssl * (100.f - ds) + ssu * ds) * 0.01f +
                              (stl * (500.f - dt) + stu * dt) * 0.002f)
                           : 0.f;
            sc[i][j] += del;
        }
    }
    // softmax over all 128 cols, then post-softmax ragged mask
#pragma unroll
    for (int i = 0; i < 2; i++) {
        float mx = sc[i][0];
#pragma unroll
        for (int j = 1; j < 8; j++) mx = fmaxf(mx, sc[i][j]);
#pragma unroll
        for (int off = 1; off < 16; off <<= 1) mx = fmaxf(mx, __shfl_xor(mx, off, 64));
        float sum = 0.f;
#pragma unroll
        for (int j = 0; j < 8; j++) {
            sc[i][j] = __expf(sc[i][j] - mx);
            sum += sc[i][j];
        }
#pragma unroll
        for (int off = 1; off < 16; off <<= 1) sum += __shfl_xor(sum, off, 64);
        float inv = 1.f / sum;
        int m = chunk * 32 + ty + 16 * i;
        bool vm = m < len;
#pragma unroll
        for (int j = 0; j < 8; j++) {
            int p = tx + 16 * j;
            attn[ty + 16 * i][p] = (vm && p < len) ? sc[i][j] * inv : 0.f;
        }
    }
    __syncthreads();

    float pv[2][4];
#pragma unroll
    for (int i = 0; i < 2; i++)
#pragma unroll
        for (int u = 0; u < 4; u++) pv[i][u] = 0.f;

    for (int pp = 0; pp < MM; pp += 4) {
        float4 a4[2], v4[4];
#pragma unroll
        for (int i = 0; i < 2; i++) a4[i] = *(const float4*)&attn[ty + 16 * i][pp];
#pragma unroll
        for (int u = 0; u < 4; u++) v4[u] = *(const float4*)&vl[pp + u][4 * tx];
#pragma unroll
        for (int i = 0; i < 2; i++) {
            pv[i][0] += a4[i].x * v4[0].x + a4[i].y * v4[1].x + a4[i].z * v4[2].x + a4[i].w * v4[3].x;
            pv[i][1] += a4[i].x * v4[0].y + a4[i].y * v4[1].y + a4[i].z * v4[2].y + a4[i].w * v4[3].y;
            pv[i][2] += a4[i].x * v4[0].z + a4[i].y * v4[1].z + a4[i].z * v4[2].z + a4[i].w * v4[3].z;
            pv[i][3] += a4[i].x * v4[0].w + a4[i].y * v4[1].w + a4[i].z * v4[2].w + a4[i].w * v4[3].w;
        }
    }

#pragma unroll
    for (int i = 0; i < 2; i++) {
        int m = chunk * 32 + ty + 16 * i;
        bool vm = m < len;
        int m1 = vm ? 1 : 0;
        int loc = traj[((size_t)(n * MM + m)) * 3 + 1];
        float rs = vm ? rowsum[loc - 1] : 0.f;
        float vv = ldf(vec, (size_t)(n * MM + m), bf);
        float Svsl = rs;
        float Svsu = 100.f * 8192.f - rs;
        float Svtl = vv * 8192.f;
        float Svtu = (500.f - vv) * 8192.f;
        uint32_t pk[2];
        float hv[4];
#pragma unroll
        for (int u = 0; u < 4; u++) {
            int d = 4 * tx + u;
            float esl = ldf(emb_sl, m1 * DD + d, bf);
            float esu = ldf(emb_su, m1 * DD + d, bf);
            float etl = ldf(emb_tl, m1 * DD + d, bf);
            float etu = ldf(emb_tu, m1 * DD + d, bf);
            float d2 = (esl * Svsu + esu * Svsl) * 0.01f + (etl * Svtu + etu * Svtl) * 0.002f;
            hv[u] = pv[i][u] * d2;
        }
        pk[0] = (uint32_t)f2bf(hv[0]) | ((uint32_t)f2bf(hv[1]) << 16);
        pk[1] = (uint32_t)f2bf(hv[2]) | ((uint32_t)f2bf(hv[3]) << 16);
        *(uint2*)(hg + ((size_t)(n * MM + m)) * DD + 4 * tx) = make_uint2(pk[0], pk[1]);
    }
}

// ---------------- K3: out = h @ W_out.T + b_out  (8192x64 @ 64x8192), bf16 MFMA ----------------
// Changes vs prev round: (1) striped wave-private LDS transpose (17 KB vs 68 KB -> 4 blocks/CU
// instead of 2, this is now a pure-memory kernel and wants wave supply); (2) skip the wlo
// residual plane when inputs are bf16 (it is identically zero then); (3) __launch_bounds__(256,4).
__global__ __launch_bounds__(256, 4) void k_out(const uint16_t* __restrict__ hg,
                                                const int* __restrict__ flag,
                                                const uint16_t* __restrict__ whi,
                                                const uint16_t* __restrict__ wlo,
                                                const void* __restrict__ bout,
                                                void* __restrict__ out) {
    bool bf = flag[0] != 0;
    int ct = blockIdx.x;
    int rt = blockIdx.y;
    int t = threadIdx.x;
    int w = t >> 6, l = t & 63;
    int wr = w >> 1, wc = w & 1;
    int row0 = rt * 128 + wr * 64;  // wave's 64x64 output tile origin
    int col0 = ct * 128 + wc * 64;
    int lr = l & 15;          // row (A) / col (B) within 16-tile
    int kb = (l >> 4) * 8;    // k-base within 32-slice

    f32x4 acc[4][4];
#pragma unroll
    for (int i = 0; i < 4; i++)
#pragma unroll
        for (int j = 0; j < 4; j++) acc[i][j] = (f32x4){0.f, 0.f, 0.f, 0.f};

#pragma unroll
    for (int s = 0; s < 2; s++) {  // two K=32 slices of K=64
        bf16x8 af[4], bh[4];
#pragma unroll
        for (int i = 0; i < 4; i++)
            af[i] = *(const bf16x8*)(hg + (size_t)(row0 + i * 16 + lr) * DD + s * 32 + kb);
#pragma unroll
        for (int j = 0; j < 4; j++)
            bh[j] = *(const bf16x8*)(whi + (size_t)(col0 + j * 16 + lr) * DD + s * 32 + kb);
#pragma unroll
        for (int i = 0; i < 4; i++)
#pragma unroll
            for (int j = 0; j < 4; j++)
                acc[i][j] = __builtin_amdgcn_mfma_f32_16x16x32_bf16(af[i], bh[j], acc[i][j], 0, 0, 0);
        if (!bf) {  // fp32 inputs: add the W_out residual plane (uniform branch)
            bf16x8 bl[4];
#pragma unroll
            for (int j = 0; j < 4; j++)
                bl[j] = *(const bf16x8*)(wlo + (size_t)(col0 + j * 16 + lr) * DD + s * 32 + kb);
#pragma unroll
            for (int i = 0; i < 4; i++)
#pragma unroll
                for (int j = 0; j < 4; j++)
                    acc[i][j] =
                        __builtin_amdgcn_mfma_f32_16x16x32_bf16(af[i], bl[j], acc[i][j], 0, 0, 0);
        }
    }

    // bias for this lane's 4 contiguous output cols in the readback layout
    int cb = col0 + lr * 4;
    float b0 = ldf(bout, cb + 0, bf), b1 = ldf(bout, cb + 1, bf);
    float b2 = ldf(bout, cb + 2, bf), b3 = ldf(bout, cb + 3, bf);

    // striped wave-private LDS transpose: one 16-row stripe at a time (no barriers:
    // same-wave DS ordering; compiler inserts lgkmcnt waits on the dependences).
    // C/D frag: col = lane&15, row = (lane>>4)*4 + q  (m89-verified layout).
    __shared__ float st[4][16][68];
#pragma unroll
    for (int i = 0; i < 4; i++) {
#pragma unroll
        for (int j = 0; j < 4; j++)
#pragma unroll
            for (int q = 0; q < 4; q++)
                st[w][(l >> 4) * 4 + q][j * 16 + lr] = acc[i][j][q];
#pragma unroll
        for (int it = 0; it < 4; it++) {
            int r = it * 4 + (l >> 4);
            float4 v = *(const float4*)&st[w][r][lr * 4];
            v.x += b0;
            v.y += b1;
            v.z += b2;
            v.w += b3;
            size_t gr = (size_t)(row0 + i * 16 + r) * LL + cb;
            if (bf) {
                uint32_t p0 = (uint32_t)f2bf(v.x) | ((uint32_t)f2bf(v.y) << 16);
                uint32_t p1 = (uint32_t)f2bf(v.z) | ((uint32_t)f2bf(v.w) << 16);
                *(uint2*)((uint16_t*)out + gr) = make_uint2(p0, p1);
            } else {
                *(float4*)((float*)out + gr) = v;
            }
        }
    }
}

extern "C" void kernel_launch(void* const* d_in, const int* in_sizes, int n_in,
                              void* d_out, int out_size, void* d_ws, size_t ws_size,
                              hipStream_t stream) {
    const int* traj     = (const int*)d_in[0];
    const void* mat1    = d_in[1];
    const void* mat2s   = d_in[2];
    const void* vec     = d_in[3];
    const int* traj_len = (const int*)d_in[4];
    const void* emb_t   = d_in[5];
    const void* emb_l   = d_in[6];
    const void* emb_u   = d_in[7];
    const void* emb_su  = d_in[8];
    const void* emb_sl  = d_in[9];
    const void* emb_tu  = d_in[10];
    const void* emb_tl  = d_in[11];
    const void* Wq      = d_in[12];
    const void* Wk      = d_in[13];
    const void* Wv      = d_in[14];
    const void* Wout    = d_in[15];
    const void* bout    = d_in[16];

    // ws layout: flag (64B) | rowsum 8192 f32 (32KB) | q,k,v,h bf16 (1MB each)
    //            | wout_hi bf16 (1MB) | wout_lo bf16 (1MB)  ≈ 6.25MB
    char* W = (char*)d_ws;
    int* flag = (int*)W;
    float* rowsum = (float*)(W + 64);
    uint16_t* qg = (uint16_t*)(W + 64 + 32768);
    uint16_t* kg = qg + (size_t)LL * DD;
    uint16_t* vg = kg + (size_t)LL * DD;
    uint16_t* hg = vg + (size_t)LL * DD;
    uint16_t* whi = hg + (size_t)LL * DD;
    uint16_t* wlo = whi + (size_t)LL * DD;

    k_detect<<<dim3(1), dim3(256), 0, stream>>>((const uint32_t*)emb_l, flag);
    k_wprep<<<dim3(512), dim3(256), 0, stream>>>(Wout, flag, whi, wlo);
    k_rowsum<<<dim3(LL), dim3(256), 0, stream>>>(mat2s, flag, rowsum);
    k_qkv<<<dim3(NB, 3), dim3(256), 0, stream>>>(traj, flag, emb_t, emb_l, emb_u, Wq, Wk, Wv, qg,
                                                 kg, vg);
    k_attn<<<dim3(4, NB), dim3(256), 0, stream>>>(traj, traj_len, flag, mat1, vec, emb_su, emb_sl,
                                                  emb_tu, emb_tl, rowsum, qg, kg, vg, hg);
    k_out<<<dim3(64, 64), dim3(256), 0, stream>>>(hg, flag, whi, wlo, bout, d_out);
}

// Round 3
// 555.148 us; speedup vs baseline: 1.2628x; 1.0278x over previous
//
#include <hip/hip_runtime.h>
#include <stdint.h>

#define NB 64
#define MM 128
#define LL 8192
#define DD 64

using f32x4 = __attribute__((ext_vector_type(4))) float;
using bf16x8 = __attribute__((ext_vector_type(8))) short;

__device__ __forceinline__ float bf2f(uint32_t u16) {
    uint32_t v = u16 << 16;
    float f;
    __builtin_memcpy(&f, &v, 4);
    return f;
}
__device__ __forceinline__ uint16_t f2bf(float f) {
    uint32_t x;
    __builtin_memcpy(&x, &f, 4);
    uint32_t r = x + 0x7FFFu + ((x >> 16) & 1u);
    return (uint16_t)(r >> 16);
}
// runtime-dtype scalar/vec4 loads (bf = "input array is bf16")
__device__ __forceinline__ float ldf(const void* p, size_t i, bool bf) {
    if (bf) return bf2f(((const uint16_t*)p)[i]);
    return ((const float*)p)[i];
}
__device__ __forceinline__ float4 ldf4(const void* p, size_t i, bool bf) {  // i must be 4-aligned
    if (bf) {
        uint2 u = *(const uint2*)((const uint16_t*)p + i);
        return make_float4(bf2f(u.x & 0xffffu), bf2f(u.x >> 16), bf2f(u.y & 0xffffu),
                           bf2f(u.y >> 16));
    }
    return *(const float4*)((const float*)p + i);
}
// fixed bf16 x4 load (internal ws tensors)
__device__ __forceinline__ float4 ldb4(const uint16_t* p, size_t i) {
    uint2 u = *(const uint2*)(p + i);
    return make_float4(bf2f(u.x & 0xffffu), bf2f(u.x >> 16), bf2f(u.y & 0xffffu), bf2f(u.y >> 16));
}

// ---- K0: detect whether float inputs are bf16 (flag=1) or fp32 (flag=0) ----
__global__ __launch_bounds__(256) void k_detect(const uint32_t* __restrict__ p,
                                                int* __restrict__ flag) {
    int t = threadIdx.x;
    int cnt = 0, nz = 0;
    for (int i = t; i < 4096; i += 256) {
        uint32_t w = p[64 + i];
        uint32_t lo = w & 0xffffu;
        if (lo) {
            nz++;
            uint32_t e = (lo >> 7) & 0xffu;
            if (e >= 100 && e <= 130) cnt++;
        }
    }
#pragma unroll
    for (int off = 32; off; off >>= 1) {
        cnt += __shfl_xor(cnt, off, 64);
        nz += __shfl_xor(nz, off, 64);
    }
    __shared__ int sc[4], sn[4];
    if ((t & 63) == 0) {
        sc[t >> 6] = cnt;
        sn[t >> 6] = nz;
    }
    __syncthreads();
    if (t == 0) {
        int C = sc[0] + sc[1] + sc[2] + sc[3];
        int Z = sn[0] + sn[1] + sn[2] + sn[3];
        flag[0] = (2 * C > Z) ? 1 : 0;
    }
}

// ---- K0b: W_out -> bf16 hi + bf16 residual (split-precision for MFMA) ----
__global__ __launch_bounds__(256) void k_wprep(const void* __restrict__ Wout,
                                               const int* __restrict__ flag,
                                               uint16_t* __restrict__ whi,
                                               uint16_t* __restrict__ wlo) {
    bool bf = flag[0] != 0;
    int i = blockIdx.x * 256 + threadIdx.x;  // group of 4 elems
    if (bf) {
        uint2 u = *((const uint2*)Wout + i);
        *((uint2*)whi + i) = u;
        *((uint2*)wlo + i) = make_uint2(0u, 0u);
    } else {
        float4 f = *((const float4*)Wout + i);
        uint16_t h0 = f2bf(f.x), h1 = f2bf(f.y), h2 = f2bf(f.z), h3 = f2bf(f.w);
        *((uint2*)whi + i) = make_uint2((uint32_t)h0 | ((uint32_t)h1 << 16),
                                        (uint32_t)h2 | ((uint32_t)h3 << 16));
        uint16_t l0 = f2bf(f.x - bf2f(h0)), l1 = f2bf(f.y - bf2f(h1));
        uint16_t l2 = f2bf(f.z - bf2f(h2)), l3 = f2bf(f.w - bf2f(h3));
        *((uint2*)wlo + i) = make_uint2((uint32_t)l0 | ((uint32_t)l1 << 16),
                                        (uint32_t)l2 | ((uint32_t)l3 << 16));
    }
}

// ---------------- K1: row sums of mat2s (L x L) -> rowsum[L] fp32 ----------------
__global__ __launch_bounds__(256) void k_rowsum(const void* __restrict__ mat2s,
                                                const int* __restrict__ flag,
                                                float* __restrict__ rowsum) {
    bool bf = flag[0] != 0;
    int row = blockIdx.x;
    float s = 0.f;
    if (bf) {
        const uint4* p4 = (const uint4*)((const uint16_t*)mat2s + (size_t)row * LL);
#pragma unroll
        for (int c = 0; c < 4; c++) {
            uint4 u = p4[c * 256 + threadIdx.x];
            uint32_t w[4] = {u.x, u.y, u.z, u.w};
#pragma unroll
            for (int q = 0; q < 4; q++) s += bf2f(w[q] & 0xffffu) + bf2f(w[q] >> 16);
        }
    } else {
        const float4* p4 = (const float4*)((const float*)mat2s + (size_t)row * LL);
#pragma unroll
        for (int c = 0; c < 8; c++) {
            float4 v = p4[c * 256 + threadIdx.x];
            s += v.x + v.y + v.z + v.w;
        }
    }
#pragma unroll
    for (int off = 32; off; off >>= 1) s += __shfl_xor(s, off, 64);
    __shared__ float red[4];
    if ((threadIdx.x & 63) == 0) red[threadIdx.x >> 6] = s;
    __syncthreads();
    if (threadIdx.x == 0) rowsum[row] = red[0] + red[1] + red[2] + red[3];
}

// ---------------- K2a: joint = emb gather; q,k,v = joint @ W.T ----------------
__global__ __launch_bounds__(256) void k_qkv(
    const int* __restrict__ traj, const int* __restrict__ flag, const void* __restrict__ emb_t,
    const void* __restrict__ emb_l, const void* __restrict__ emb_u, const void* __restrict__ Wq,
    const void* __restrict__ Wk, const void* __restrict__ Wv, uint16_t* __restrict__ qg,
    uint16_t* __restrict__ kg, uint16_t* __restrict__ vg) {
    bool bf = flag[0] != 0;
    int n = blockIdx.x;
    int w = blockIdx.y;  // 0=q, 1=k, 2=v
    int t = threadIdx.x;
    __shared__ float joint[MM][DD + 4];
    __shared__ float Wl[DD][DD + 4];
    __shared__ int iu[MM], il[MM], it[MM];

    if (t < MM) {
        iu[t] = traj[((size_t)(n * MM + t)) * 3 + 0];
        il[t] = traj[((size_t)(n * MM + t)) * 3 + 1];
        int tm = traj[((size_t)(n * MM + t)) * 3 + 2];
        it[t] = (tm - 1) % 168 + 1;
    }
    const void* Ws[3] = {Wq, Wk, Wv};
    uint16_t* outs[3] = {qg, kg, vg};
    for (int i = t; i < DD * 16; i += 256) {
        int r = i >> 4, c = (i & 15) * 4;
        float4 a = ldf4(Ws[w], (size_t)r * DD + c, bf);
        Wl[r][c] = a.x;
        Wl[r][c + 1] = a.y;
        Wl[r][c + 2] = a.z;
        Wl[r][c + 3] = a.w;
    }
    __syncthreads();

    for (int i = t; i < MM * 16; i += 256) {
        int m = i >> 4, c = (i & 15) * 4;
        float4 a = ldf4(emb_t, (size_t)it[m] * DD + c, bf);
        float4 b = ldf4(emb_l, (size_t)il[m] * DD + c, bf);
        float4 d = ldf4(emb_u, (size_t)iu[m] * DD + c, bf);
        joint[m][c]     = a.x + b.x + d.x;
        joint[m][c + 1] = a.y + b.y + d.y;
        joint[m][c + 2] = a.z + b.z + d.z;
        joint[m][c + 3] = a.w + b.w + d.w;
    }
    __syncthreads();

    int m = t >> 1;
    int dbase = (t & 1) * 32;
    float acc[32];
#pragma unroll
    for (int j = 0; j < 32; j++) acc[j] = 0.f;
    for (int kk = 0; kk < DD; kk += 4) {
        float4 j4 = *(const float4*)&joint[m][kk];
#pragma unroll
        for (int j = 0; j < 32; j++) {
            float4 w4 = *(const float4*)&Wl[dbase + j][kk];
            acc[j] += j4.x * w4.x + j4.y * w4.y + j4.z * w4.z + j4.w * w4.w;
        }
    }
    uint32_t* og = (uint32_t*)(outs[w] + ((size_t)(n * MM + m)) * DD + dbase);
#pragma unroll
    for (int j = 0; j < 32; j += 2)
        og[j >> 1] = (uint32_t)f2bf(acc[j]) | ((uint32_t)f2bf(acc[j + 1]) << 16);
}

// ---------------- K2b: attention + delta scalars + h = self_attn * delta2 ----------------
// Round-3 changes: (1) K/V staged as raw bf16 in LDS (ushort[128][68]; stride 136 B keeps
// b64 reads conflict-free: banks 2*tx mod 32 cover all 32) -> LDS 95.2 KB -> 60.4 KB ->
// 2 blocks/CU instead of 1 (this kernel was 1 wave/SIMD, fully latency-exposed);
// (2) emb-sum scalars via one wave-parallel shuffle reduce instead of 256 serial scalar
// loads per thread; (3) mat1 (ds,dt) pairs loaded as one uint32/float2; (4) delta algebra
// folded to 2 FMA: del = (ssl+stl) + ds*(ssu-ssl)/100 + dt*(stu-stl)/500.
__global__ __launch_bounds__(256, 2) void k_attn(
    const int* __restrict__ traj, const int* __restrict__ traj_len, const int* __restrict__ flag,
    const void* __restrict__ mat1, const void* __restrict__ vec, const void* __restrict__ emb_su,
    const void* __restrict__ emb_sl, const void* __restrict__ emb_tu,
    const void* __restrict__ emb_tl, const float* __restrict__ rowsum,
    const uint16_t* __restrict__ qg, const uint16_t* __restrict__ kg,
    const uint16_t* __restrict__ vg, uint16_t* __restrict__ hg) {
    bool bf = flag[0] != 0;
    int chunk = blockIdx.x;  // 0..3 (32 rows each)
    int n = blockIdx.y;
    int t = threadIdx.x;
    __shared__ uint16_t kl16[MM][DD + 4];  // raw bf16 K tile
    __shared__ uint16_t vl16[MM][DD + 4];  // raw bf16 V tile
    __shared__ float ql[32][DD + 4];
    __shared__ float attn[32][MM + 4];
    __shared__ float s4[4];

    int len = traj_len[n];

    for (int i = t; i < MM * 16; i += 256) {
        int r = i >> 4, c = (i & 15) * 4;
        *(uint2*)&kl16[r][c] = *(const uint2*)(kg + ((size_t)(n * MM + r)) * DD + c);
        *(uint2*)&vl16[r][c] = *(const uint2*)(vg + ((size_t)(n * MM + r)) * DD + c);
    }
    for (int i = t; i < 32 * 16; i += 256) {
        int r = i >> 4, c = (i & 15) * 4;
        *(float4*)&ql[r][c] = ldb4(qg, ((size_t)(n * MM + chunk * 32 + r)) * DD + c);
    }
    if (t < 64) {
        float a = ldf(emb_sl, DD + t, bf);
        float b = ldf(emb_su, DD + t, bf);
        float c = ldf(emb_tl, DD + t, bf);
        float d = ldf(emb_tu, DD + t, bf);
#pragma unroll
        for (int off = 32; off; off >>= 1) {
            a += __shfl_xor(a, off, 64);
            b += __shfl_xor(b, off, 64);
            c += __shfl_xor(c, off, 64);
            d += __shfl_xor(d, off, 64);
        }
        if (t == 0) {
            s4[0] = a;
            s4[1] = b;
            s4[2] = c;
            s4[3] = d;
        }
    }
    __syncthreads();
    float ssl = s4[0], ssu = s4[1], stl = s4[2], stu = s4[3];
    float dc0 = ssl + stl;
    float dcs = (ssu - ssl) * 0.01f;
    float dct = (stu - stl) * 0.002f;

    int tx = t & 15, ty = t >> 4;
    float sc[2][8];
#pragma unroll
    for (int i = 0; i < 2; i++)
#pragma unroll
        for (int j = 0; j < 8; j++) sc[i][j] = 0.f;

    for (int kk = 0; kk < DD; kk += 4) {
        float4 q4[2], k4[8];
#pragma unroll
        for (int i = 0; i < 2; i++) q4[i] = *(const float4*)&ql[ty + 16 * i][kk];
#pragma unroll
        for (int j = 0; j < 8; j++) {
            uint2 u = *(const uint2*)&kl16[tx + 16 * j][kk];
            k4[j] = make_float4(bf2f(u.x & 0xffffu), bf2f(u.x >> 16), bf2f(u.y & 0xffffu),
                                bf2f(u.y >> 16));
        }
#pragma unroll
        for (int i = 0; i < 2; i++)
#pragma unroll
            for (int j = 0; j < 8; j++)
                sc[i][j] += q4[i].x * k4[j].x + q4[i].y * k4[j].y + q4[i].z * k4[j].z +
                            q4[i].w * k4[j].w;
    }
#pragma unroll
    for (int i = 0; i < 2; i++) {
        int m = chunk * 32 + ty + 16 * i;
        bool vm = m < len;
#pragma unroll
        for (int j = 0; j < 8; j++) {
            int p = tx + 16 * j;
            size_t base = (((size_t)(n * MM + m)) * MM + p) * 2;
            float ds, dt;
            if (bf) {
                uint32_t u = *(const uint32_t*)((const uint16_t*)mat1 + base);
                ds = bf2f(u & 0xffffu);
                dt = bf2f(u >> 16);
            } else {
                float2 f2 = *(const float2*)((const float*)mat1 + base);
                ds = f2.x;
                dt = f2.y;
            }
            bool v2 = vm && (p < len);
            sc[i][j] += v2 ? (dc0 + ds * dcs + dt * dct) : 0.f;
        }
    }
    // softmax over all 128 cols, then post-softmax ragged mask
#pragma unroll
    for (int i = 0; i < 2; i++) {
        float mx = sc[i][0];
#pragma unroll
        for (int j = 1; j < 8; j++) mx = fmaxf(mx, sc[i][j]);
#pragma unroll
        for (int off = 1; off < 16; off <<= 1) mx = fmaxf(mx, __shfl_xor(mx, off, 64));
        float sum = 0.f;
#pragma unroll
        for (int j = 0; j < 8; j++) {
            sc[i][j] = __expf(sc[i][j] - mx);
            sum += sc[i][j];
        }
#pragma unroll
        for (int off = 1; off < 16; off <<= 1) sum += __shfl_xor(sum, off, 64);
        float inv = 1.f / sum;
        int m = chunk * 32 + ty + 16 * i;
        bool vm = m < len;
#pragma unroll
        for (int j = 0; j < 8; j++) {
            int p = tx + 16 * j;
            attn[ty + 16 * i][p] = (vm && p < len) ? sc[i][j] * inv : 0.f;
        }
    }
    __syncthreads();

    float pv[2][4];
#pragma unroll
    for (int i = 0; i < 2; i++)
#pragma unroll
        for (int u = 0; u < 4; u++) pv[i][u] = 0.f;

    for (int pp = 0; pp < MM; pp += 4) {
        float4 a4[2], v4[4];
#pragma unroll
        for (int i = 0; i < 2; i++) a4[i] = *(const float4*)&attn[ty + 16 * i][pp];
#pragma unroll
        for (int u = 0; u < 4; u++) {
            uint2 wv = *(const uint2*)&vl16[pp + u][4 * tx];
            v4[u] = make_float4(bf2f(wv.x & 0xffffu), bf2f(wv.x >> 16), bf2f(wv.y & 0xffffu),
                                bf2f(wv.y >> 16));
        }
#pragma unroll
        for (int i = 0; i < 2; i++) {
            pv[i][0] += a4[i].x * v4[0].x + a4[i].y * v4[1].x + a4[i].z * v4[2].x + a4[i].w * v4[3].x;
            pv[i][1] += a4[i].x * v4[0].y + a4[i].y * v4[1].y + a4[i].z * v4[2].y + a4[i].w * v4[3].y;
            pv[i][2] += a4[i].x * v4[0].z + a4[i].y * v4[1].z + a4[i].z * v4[2].z + a4[i].w * v4[3].z;
            pv[i][3] += a4[i].x * v4[0].w + a4[i].y * v4[1].w + a4[i].z * v4[2].w + a4[i].w * v4[3].w;
        }
    }

#pragma unroll
    for (int i = 0; i < 2; i++) {
        int m = chunk * 32 + ty + 16 * i;
        bool vm = m < len;
        int m1 = vm ? 1 : 0;
        int loc = traj[((size_t)(n * MM + m)) * 3 + 1];
        float rs = vm ? rowsum[loc - 1] : 0.f;
        float vv = ldf(vec, (size_t)(n * MM + m), bf);
        float Svsl = rs;
        float Svsu = 100.f * 8192.f - rs;
        float Svtl = vv * 8192.f;
        float Svtu = (500.f - vv) * 8192.f;
        uint32_t pk[2];
        float hv[4];
#pragma unroll
        for (int u = 0; u < 4; u++) {
            int d = 4 * tx + u;
            float esl = ldf(emb_sl, m1 * DD + d, bf);
            float esu = ldf(emb_su, m1 * DD + d, bf);
            float etl = ldf(emb_tl, m1 * DD + d, bf);
            float etu = ldf(emb_tu, m1 * DD + d, bf);
            float d2 = (esl * Svsu + esu * Svsl) * 0.01f + (etl * Svtu + etu * Svtl) * 0.002f;
            hv[u] = pv[i][u] * d2;
        }
        pk[0] = (uint32_t)f2bf(hv[0]) | ((uint32_t)f2bf(hv[1]) << 16);
        pk[1] = (uint32_t)f2bf(hv[2]) | ((uint32_t)f2bf(hv[3]) << 16);
        *(uint2*)(hg + ((size_t)(n * MM + m)) * DD + 4 * tx) = make_uint2(pk[0], pk[1]);
    }
}

// ---------------- K3: out = h @ W_out.T + b_out  (8192x64 @ 64x8192), bf16 MFMA ----------------
__global__ __launch_bounds__(256, 4) void k_out(const uint16_t* __restrict__ hg,
                                                const int* __restrict__ flag,
                                                const uint16_t* __restrict__ whi,
                                                const uint16_t* __restrict__ wlo,
                                                const void* __restrict__ bout,
                                                void* __restrict__ out) {
    bool bf = flag[0] != 0;
    int ct = blockIdx.x;
    int rt = blockIdx.y;
    int t = threadIdx.x;
    int w = t >> 6, l = t & 63;
    int wr = w >> 1, wc = w & 1;
    int row0 = rt * 128 + wr * 64;  // wave's 64x64 output tile origin
    int col0 = ct * 128 + wc * 64;
    int lr = l & 15;          // row (A) / col (B) within 16-tile
    int kb = (l >> 4) * 8;    // k-base within 32-slice

    f32x4 acc[4][4];
#pragma unroll
    for (int i = 0; i < 4; i++)
#pragma unroll
        for (int j = 0; j < 4; j++) acc[i][j] = (f32x4){0.f, 0.f, 0.f, 0.f};

#pragma unroll
    for (int s = 0; s < 2; s++) {  // two K=32 slices of K=64
        bf16x8 af[4], bh[4];
#pragma unroll
        for (int i = 0; i < 4; i++)
            af[i] = *(const bf16x8*)(hg + (size_t)(row0 + i * 16 + lr) * DD + s * 32 + kb);
#pragma unroll
        for (int j = 0; j < 4; j++)
            bh[j] = *(const bf16x8*)(whi + (size_t)(col0 + j * 16 + lr) * DD + s * 32 + kb);
#pragma unroll
        for (int i = 0; i < 4; i++)
#pragma unroll
            for (int j = 0; j < 4; j++)
                acc[i][j] = __builtin_amdgcn_mfma_f32_16x16x32_bf16(af[i], bh[j], acc[i][j], 0, 0, 0);
        if (!bf) {  // fp32 inputs: add the W_out residual plane (uniform branch)
            bf16x8 bl[4];
#pragma unroll
            for (int j = 0; j < 4; j++)
                bl[j] = *(const bf16x8*)(wlo + (size_t)(col0 + j * 16 + lr) * DD + s * 32 + kb);
#pragma unroll
            for (int i = 0; i < 4; i++)
#pragma unroll
                for (int j = 0; j < 4; j++)
                    acc[i][j] =
                        __builtin_amdgcn_mfma_f32_16x16x32_bf16(af[i], bl[j], acc[i][j], 0, 0, 0);
        }
    }

    // bias for this lane's 4 contiguous output cols in the readback layout
    int cb = col0 + lr * 4;
    float b0 = ldf(bout, cb + 0, bf), b1 = ldf(bout, cb + 1, bf);
    float b2 = ldf(bout, cb + 2, bf), b3 = ldf(bout, cb + 3, bf);

    // striped wave-private LDS transpose (no barriers: same-wave DS ordering).
    // C/D frag: col = lane&15, row = (lane>>4)*4 + q  (m89-verified layout).
    __shared__ float st[4][16][68];
#pragma unroll
    for (int i = 0; i < 4; i++) {
#pragma unroll
        for (int j = 0; j < 4; j++)
#pragma unroll
            for (int q = 0; q < 4; q++)
                st[w][(l >> 4) * 4 + q][j * 16 + lr] = acc[i][j][q];
#pragma unroll
        for (int it = 0; it < 4; it++) {
            int r = it * 4 + (l >> 4);
            float4 v = *(const float4*)&st[w][r][lr * 4];
            v.x += b0;
            v.y += b1;
            v.z += b2;
            v.w += b3;
            size_t gr = (size_t)(row0 + i * 16 + r) * LL + cb;
            if (bf) {
                uint32_t p0 = (uint32_t)f2bf(v.x) | ((uint32_t)f2bf(v.y) << 16);
                uint32_t p1 = (uint32_t)f2bf(v.z) | ((uint32_t)f2bf(v.w) << 16);
                *(uint2*)((uint16_t*)out + gr) = make_uint2(p0, p1);
            } else {
                *(float4*)((float*)out + gr) = v;
            }
        }
    }
}

extern "C" void kernel_launch(void* const* d_in, const int* in_sizes, int n_in,
                              void* d_out, int out_size, void* d_ws, size_t ws_size,
                              hipStream_t stream) {
    const int* traj     = (const int*)d_in[0];
    const void* mat1    = d_in[1];
    const void* mat2s   = d_in[2];
    const void* vec     = d_in[3];
    const int* traj_len = (const int*)d_in[4];
    const void* emb_t   = d_in[5];
    const void* emb_l   = d_in[6];
    const void* emb_u   = d_in[7];
    const void* emb_su  = d_in[8];
    const void* emb_sl  = d_in[9];
    const void* emb_tu  = d_in[10];
    const void* emb_tl  = d_in[11];
    const void* Wq      = d_in[12];
    const void* Wk      = d_in[13];
    const void* Wv      = d_in[14];
    const void* Wout    = d_in[15];
    const void* bout    = d_in[16];

    // ws layout: flag (64B) | rowsum 8192 f32 (32KB) | q,k,v,h bf16 (1MB each)
    //            | wout_hi bf16 (1MB) | wout_lo bf16 (1MB)  ≈ 6.25MB
    char* W = (char*)d_ws;
    int* flag = (int*)W;
    float* rowsum = (float*)(W + 64);
    uint16_t* qg = (uint16_t*)(W + 64 + 32768);
    uint16_t* kg = qg + (size_t)LL * DD;
    uint16_t* vg = kg + (size_t)LL * DD;
    uint16_t* hg = vg + (size_t)LL * DD;
    uint16_t* whi = hg + (size_t)LL * DD;
    uint16_t* wlo = whi + (size_t)LL * DD;

    k_detect<<<dim3(1), dim3(256), 0, stream>>>((const uint32_t*)emb_l, flag);
    k_wprep<<<dim3(512), dim3(256), 0, stream>>>(Wout, flag, whi, wlo);
    k_rowsum<<<dim3(LL), dim3(256), 0, stream>>>(mat2s, flag, rowsum);
    k_qkv<<<dim3(NB, 3), dim3(256), 0, stream>>>(traj, flag, emb_t, emb_l, emb_u, Wq, Wk, Wv, qg,
                                                 kg, vg);
    k_attn<<<dim3(4, NB), dim3(256), 0, stream>>>(traj, traj_len, flag, mat1, vec, emb_su, emb_sl,
                                                  emb_tu, emb_tl, rowsum, qg, kg, vg, hg);
    k_out<<<dim3(64, 64), dim3(256), 0, stream>>>(hg, flag, whi, wlo, bout, d_out);
}